// Round 7
// baseline (423.454 us; speedup 1.0000x reference)
//
#include <hip/hip_runtime.h>
#include <hip/hip_bf16.h>

#define H 10
#define HP 16          // padded hidden (MFMA tile dim)
#define T_LEN 2048
#define BATCH 8192

typedef _Float16 h4_t __attribute__((ext_vector_type(4)));
typedef float    f4_t __attribute__((ext_vector_type(4)));

// ---------------------------------------------------------------------------
// Kernel 1: Bp = expm(triu(A,1) - triu(A,1)^T) in fp64, PADDED to 16x16
// (zeros outside 10x10), fp32 into ws. Fixed scaling s=8, 16 Taylor terms,
// 8 squarings.
// ---------------------------------------------------------------------------
__global__ void expm_kernel(const float* __restrict__ A, float* __restrict__ Bout) {
    __shared__ double S[H][H];
    __shared__ double P[H][H];
    __shared__ double E[H][H];
    const int tid = threadIdx.x;
    const int i = tid / H, j = tid % H;
    if (tid < H * H) {
        double a = 0.0;
        if (i < j) a = (double)A[i * H + j];
        else if (i > j) a = -(double)A[j * H + i];
        a *= (1.0 / 256.0);
        S[i][j] = a;
        P[i][j] = a;
        E[i][j] = (i == j ? 1.0 : 0.0) + a;
    }
    __syncthreads();
    for (int k = 2; k <= 16; ++k) {
        double acc = 0.0;
        if (tid < H * H) {
            for (int m = 0; m < H; ++m) acc += P[i][m] * S[m][j];
            acc *= (1.0 / (double)k);
        }
        __syncthreads();
        if (tid < H * H) { P[i][j] = acc; E[i][j] += acc; }
        __syncthreads();
    }
    for (int rr = 0; rr < 8; ++rr) {
        double acc = 0.0;
        if (tid < H * H) {
            for (int m = 0; m < H; ++m) acc += E[i][m] * E[m][j];
        }
        __syncthreads();
        if (tid < H * H) E[i][j] = acc;
        __syncthreads();
    }
    for (int idx = tid; idx < HP * HP; idx += blockDim.x) {
        const int i2 = idx / HP, j2 = idx % HP;
        Bout[idx] = (i2 < H && j2 < H) ? (float)E[i2][j2] : 0.0f;
    }
}

// ---------------------------------------------------------------------------
// Kernel 2: MFMA fixed-point recurrence, 1-MFMA critical path.
//   z = (B_hi + B_lo) . h  computed as TWO INDEPENDENT MFMAs (both read the
//   same b_hi from the previous step) + a vector add:
//       M1 = a_hi . b_hi + C(x-proj)     M2 = a_lo . b_hi + 0
//   h state is single fp16 via RNE converts (v_cvt_f16_f32) -> unbiased
//   random walk ~0.02 abs over 2048 steps. B stays 22-bit (hi+lo) because
//   its quantization error would be systematic.
//   Critical path/step: 1 MFMA latency + add + modrelu + cvt  (~105 cy vs
//   276 cy for the 3-serial-MFMA version).
//   x-prefetch: 2 chunks (16 steps) in flight to cover HBM latency.
// ---------------------------------------------------------------------------
__global__ __launch_bounds__(64)
void rnn_kernel(const float* __restrict__ x,
                const float* __restrict__ Bp,     // padded 16x16 fp32
                const float* __restrict__ Win,
                const float* __restrict__ bmod,
                const float* __restrict__ lW,
                const float* __restrict__ lb,
                float* __restrict__ out) {
    const int l = threadIdx.x;
    const int m = l & 15;                 // batch within tile / operand col
    const int q = l >> 4;                 // k/row quad
    const int n0 = q * 4;                 // hidden index base for regs
    const int batch = blockIdx.x * 16 + m;

    // A-operand (constant): a[i] = Bmat[4q+i][m], split into fp16 hi+lo
    h4_t a_hi, a_lo;
    f4_t w0v, w1v, bmv;
#pragma unroll
    for (int i = 0; i < 4; ++i) {
        const float bv = Bp[(n0 + i) * HP + m];
        const _Float16 hi = (_Float16)bv;     // RNE
        a_hi[i] = hi;
        a_lo[i] = (_Float16)(bv - (float)hi);
        const int n = n0 + i;
        w0v[i] = (n < H) ? Win[n * 2 + 0] : 0.0f;
        w1v[i] = (n < H) ? Win[n * 2 + 1] : 0.0f;
        bmv[i] = (n < H) ? bmod[n] : 0.0f;
    }

    float hs0 = 0.0f, hs1 = 0.0f, hs2 = 0.0f, hs3 = 0.0f;  // fp32 h (for epilogue)
    h4_t b_hi = {0, 0, 0, 0};                               // fp16 h state
    const f4_t zero4 = {0.0f, 0.0f, 0.0f, 0.0f};

    const float4* __restrict__ xp4 =
        (const float4*)(x + (size_t)batch * (T_LEN * 2));

    // one step-8 block: consumes 4 float4 (8 timesteps)
    auto step8 = [&](const float4& c0, const float4& c1,
                     const float4& c2, const float4& c3) {
        float xs[16];
        xs[0] = c0.x; xs[1] = c0.y; xs[2]  = c0.z; xs[3]  = c0.w;
        xs[4] = c1.x; xs[5] = c1.y; xs[6]  = c1.z; xs[7]  = c1.w;
        xs[8] = c2.x; xs[9] = c2.y; xs[10] = c2.z; xs[11] = c2.w;
        xs[12] = c3.x; xs[13] = c3.y; xs[14] = c3.z; xs[15] = c3.w;
#pragma unroll
        for (int u = 0; u < 8; ++u) {
            const float x0 = xs[2 * u], x1 = xs[2 * u + 1];
            f4_t c;
            c[0] = fmaf(x1, w1v[0], x0 * w0v[0]);
            c[1] = fmaf(x1, w1v[1], x0 * w0v[1]);
            c[2] = fmaf(x1, w1v[2], x0 * w0v[2]);
            c[3] = fmaf(x1, w1v[3], x0 * w0v[3]);

            // two INDEPENDENT MFMAs (both read prev-step b_hi)
            const f4_t m1 = __builtin_amdgcn_mfma_f32_16x16x16f16(a_hi, b_hi, c,     0, 0, 0);
            const f4_t m2 = __builtin_amdgcn_mfma_f32_16x16x16f16(a_lo, b_hi, zero4, 0, 0, 0);

            const float z0 = m1[0] + m2[0];
            const float z1 = m1[1] + m2[1];
            const float z2 = m1[2] + m2[2];
            const float z3 = m1[3] + m2[3];

            // modrelu (abs folds into the add as a VOP3 modifier)
            hs0 = __builtin_copysignf(fmaxf(fabsf(z0) + bmv[0], 0.0f), z0);
            hs1 = __builtin_copysignf(fmaxf(fabsf(z1) + bmv[1], 0.0f), z1);
            hs2 = __builtin_copysignf(fmaxf(fabsf(z2) + bmv[2], 0.0f), z2);
            hs3 = __builtin_copysignf(fmaxf(fabsf(z3) + bmv[3], 0.0f), z3);

            // RNE fp32 -> fp16 (v_cvt_f16_f32); unbiased
            b_hi[0] = (_Float16)hs0;
            b_hi[1] = (_Float16)hs1;
            b_hi[2] = (_Float16)hs2;
            b_hi[3] = (_Float16)hs3;
        }
    };

    // 2-chunks-in-flight prefetch (each chunk = 8 steps = 4 float4)
    float4 a0 = xp4[0], a1 = xp4[1], a2 = xp4[2], a3 = xp4[3];
    float4 b0 = xp4[4], b1 = xp4[5], b2 = xp4[6], b3 = xp4[7];

    for (int t0 = 0; t0 < T_LEN; t0 += 16) {
        const float4 ca0 = a0, ca1 = a1, ca2 = a2, ca3 = a3;
        if (t0 + 16 < T_LEN) {
            const int base = (t0 + 16) >> 1;
            a0 = xp4[base + 0]; a1 = xp4[base + 1];
            a2 = xp4[base + 2]; a3 = xp4[base + 3];
        }
        step8(ca0, ca1, ca2, ca3);

        const float4 cb0 = b0, cb1 = b1, cb2 = b2, cb3 = b3;
        if (t0 + 24 < T_LEN) {
            const int base = (t0 + 24) >> 1;
            b0 = xp4[base + 0]; b1 = xp4[base + 1];
            b2 = xp4[base + 2]; b3 = xp4[base + 3];
        }
        step8(cb0, cb1, cb2, cb3);
    }

    // epilogue: gather h via LDS, then the 10x10 output projection
    __shared__ float hsh[16][17];
    hsh[m][n0 + 0] = hs0;
    hsh[m][n0 + 1] = hs1;
    hsh[m][n0 + 2] = hs2;
    hsh[m][n0 + 3] = hs3;
    __syncthreads();   // single-wave block: lgkmcnt wait only
#pragma unroll
    for (int jo = 0; jo < 3; ++jo) {
        const int o = q + 4 * jo;
        if (o < H) {
            float acc = lb[o];
#pragma unroll
            for (int jj = 0; jj < H; ++jj)
                acc = fmaf(hsh[m][jj], lW[o * H + jj], acc);
            out[(size_t)batch * H + o] = acc;
        }
    }
}

extern "C" void kernel_launch(void* const* d_in, const int* in_sizes, int n_in,
                              void* d_out, int out_size, void* d_ws, size_t ws_size,
                              hipStream_t stream) {
    const float* inputs = (const float*)d_in[0];  // [8192, 2048, 2]
    const float* A      = (const float*)d_in[1];  // [10, 10]
    const float* W_in   = (const float*)d_in[2];  // [10, 2]
    const float* b_mod  = (const float*)d_in[3];  // [10]
    const float* lin_W  = (const float*)d_in[4];  // [10, 10]
    const float* lin_b  = (const float*)d_in[5];  // [10]
    float* out = (float*)d_out;                   // [8192, 10]
    float* Bpad = (float*)d_ws;                   // 256 floats scratch

    expm_kernel<<<1, 128, 0, stream>>>(A, Bpad);
    rnn_kernel<<<BATCH / 16, 64, 0, stream>>>(inputs, Bpad, W_in, b_mod,
                                              lin_W, lin_b, out);
}